// Round 10
// baseline (1057.863 us; speedup 1.0000x reference)
//
#include <hip/hip_runtime.h>
#include <hip/hip_bf16.h>

// ---------------------------------------------------------------------------
// GIN0 (GINE x3 + BN + head) forward.
// R1: CSR + per-node register aggregation (no atomics in hot path).
// R3: node MLP GEMMs on MFMA via split-bf16 (hi+lo, 3-pass).
// R5: BN stats fused into GEMM2 epilogue; single prep kernel.
// R6: gathers read a bf16 copy of h; self-term fp32.
// R8: WPN waves/node so We slice stays VGPR-resident; interleaved int2 CSR.
// R9: edge features via uniform (SGPR) loads; eid/src via 2 readlanes.
// R10: latency pipeline -- 8-edge unroll (8 gathers in flight, fits VGPR
//      budget now that per-edge state is tiny) + csr prefetch of the next
//      iteration; 4-edge + 1-edge tails.
// ---------------------------------------------------------------------------

typedef __attribute__((ext_vector_type(8))) short short8;
typedef __attribute__((ext_vector_type(4))) float floatx4;
typedef __attribute__((ext_vector_type(2))) float float2v;

__device__ __forceinline__ float2v splat2(float s) {
    float2v v; v[0] = s; v[1] = s; return v;
}

__device__ __forceinline__ float2v fma2(float s, float2v w, float2v p) {
    return __builtin_elementwise_fma(splat2(s), w, p);
}

__device__ __forceinline__ ushort f2bf_rne(float x) {
    unsigned u = __float_as_uint(x);
    unsigned r = (u + 0x7FFFu + ((u >> 16) & 1u)) >> 16;
    return (ushort)r;
}

__device__ __forceinline__ float bf2f(ushort u) {
    return __uint_as_float(((unsigned)u) << 16);
}

// ---------------- CSR build ----------------

__global__ __launch_bounds__(256) void hist_kernel(const int* __restrict__ dst,
                                                   int* __restrict__ deg, int E) {
    int i = blockIdx.x * blockDim.x + threadIdx.x;
    int stride = gridDim.x * blockDim.x;
    for (; i < E; i += stride) atomicAdd(&deg[dst[i]], 1);
}

__global__ __launch_bounds__(1024) void scan_kernel(const int* __restrict__ deg,
                                                    int* __restrict__ row_start, int N) {
    __shared__ int part[1024];
    int tid = threadIdx.x;
    int per = (N + 1023) / 1024;
    int start = tid * per;
    int end = min(start + per, N);
    int s = 0;
    for (int i = start; i < end; ++i) s += deg[i];
    part[tid] = s;
    __syncthreads();
    if (tid == 0) {
        int t = 0;
        for (int i = 0; i < 1024; ++i) {
            int v = part[i];
            part[i] = t;
            t += v;
        }
    }
    __syncthreads();
    int run = part[tid];
    for (int i = start; i < end; ++i) {
        row_start[i] = run;
        run += deg[i];
    }
    if (tid == 1023) row_start[N] = run;
}

__global__ __launch_bounds__(256) void scatter_kernel(
    const int* __restrict__ src, const int* __restrict__ dst,
    const int* __restrict__ row_start, int* __restrict__ cursor,
    int2* __restrict__ csr, int E) {
    int i = blockIdx.x * blockDim.x + threadIdx.x;
    int stride = gridDim.x * blockDim.x;
    for (; i < E; i += stride) {
        int v = dst[i];
        int p = row_start[v] + atomicAdd(&cursor[v], 1);
        csr[p] = make_int2(i, src[i]);
    }
}

// ---------------- Weight prep ----------------
__device__ __forceinline__ void wsplit(const float* W, ushort* Wth, ushort* Wtl,
                                       int K, int N, int t) {
    int k = t / N, n = t - k * N;
    float v = W[t];
    ushort hv = f2bf_rne(v);
    float hf = bf2f(hv);
    ushort lv = f2bf_rne(v - hf);
    Wth[(size_t)n * K + k] = hv;
    Wtl[(size_t)n * K + k] = lv;
}

__global__ __launch_bounds__(256) void prep_all(
    const float* W11, ushort* W11h, ushort* W11l,
    const float* W12, ushort* W12h, ushort* W12l,
    const float* W21, ushort* W21h, ushort* W21l,
    const float* W22, ushort* W22h, ushort* W22l,
    const float* W31, ushort* W31h, ushort* W31l,
    const float* W32, ushort* W32h, ushort* W32l) {
    int t = blockIdx.x * blockDim.x + threadIdx.x;
    const int s1 = 128 * 256, s2 = s1 + 256 * 256, s3 = s2 + 256 * 128;
    const int s4 = s3 + 128 * 128, s5 = s4 + 128 * 64, s6 = s5 + 64 * 64;
    if (t < s1) wsplit(W11, W11h, W11l, 128, 256, t);
    else if (t < s2) wsplit(W12, W12h, W12l, 256, 256, t - s1);
    else if (t < s3) wsplit(W21, W21h, W21l, 256, 128, t - s2);
    else if (t < s4) wsplit(W22, W22h, W22l, 128, 128, t - s3);
    else if (t < s5) wsplit(W31, W31h, W31l, 128, 64, t - s4);
    else if (t < s6) wsplit(W32, W32h, W32l, 64, 64, t - s5);
}

// ---------------- fp32 -> bf16 convert (layer-1 gather copy) --------------
__global__ __launch_bounds__(256) void f32_to_bf16(const float* __restrict__ in,
                                                   ushort* __restrict__ out, long n4) {
    long i = (long)blockIdx.x * blockDim.x + threadIdx.x;
    long stride = (long)gridDim.x * blockDim.x;
    for (; i < n4; i += stride) {
        float4 v = ((const float4*)in)[i];
        ushort4 o;
        o.x = f2bf_rne(v.x);
        o.y = f2bf_rne(v.y);
        o.z = f2bf_rne(v.z);
        o.w = f2bf_rne(v.w);
        ((ushort4*)out)[i] = o;
    }
}

// ---------------- edge MLP inner body (uniform ea, resident w) ------------
template <typename WT>
__device__ __forceinline__ float2v edge_term(const float* __restrict__ ea, int eid,
                                             const WT& w, float2v bias,
                                             float2v hv, float2v z2) {
    const float4* ep = (const float4*)(ea + (size_t)eid * 16);
    float4 ev0 = ep[0];
    float4 ev1 = ep[1];
    float4 ev2 = ep[2];
    float4 ev3 = ep[3];
    float2v p = bias;
    p = fma2(ev0.x, w[0], p);
    p = fma2(ev0.y, w[1], p);
    p = fma2(ev0.z, w[2], p);
    p = fma2(ev0.w, w[3], p);
    p = fma2(ev1.x, w[4], p);
    p = fma2(ev1.y, w[5], p);
    p = fma2(ev1.z, w[6], p);
    p = fma2(ev1.w, w[7], p);
    p = fma2(ev2.x, w[8], p);
    p = fma2(ev2.y, w[9], p);
    p = fma2(ev2.z, w[10], p);
    p = fma2(ev2.w, w[11], p);
    p = fma2(ev3.x, w[12], p);
    p = fma2(ev3.y, w[13], p);
    p = fma2(ev3.z, w[14], p);
    p = fma2(ev3.w, w[15], p);
    float2v m = p + hv;
    return __builtin_elementwise_max(m, z2);
}

// ---------------- Fused GINE aggregation ----------------
// WPN waves per node, each owning 128 channels (2/lane; We slice = 32 VGPR,
// resident). 8-edge pipelined main loop with csr prefetch; 4/1-edge tails.
template <int D, int WPN>
__global__ __launch_bounds__(256) void gine_agg_kernel(
    const float* __restrict__ h, const ushort* __restrict__ hb,
    const float* __restrict__ ea,
    const int* __restrict__ row_start, const int2* __restrict__ csr,
    const float* __restrict__ We, const float* __restrict__ be,
    ushort* __restrict__ uhi, ushort* __restrict__ ulo, int N) {
    constexpr int NPB = 4 / WPN;  // nodes per 256-thread block
    const int lane = threadIdx.x & 63;
    const int wid = threadIdx.x >> 6;
    const int ch0 = (wid % WPN) * 128 + lane * 2;

    float2v w[16];
#pragma unroll
    for (int k = 0; k < 16; ++k) w[k] = *(const float2v*)&We[k * D + ch0];
    const float2v bias = *(const float2v*)&be[ch0];

    int v = blockIdx.x * NPB + wid / WPN;
    const int vstride = gridDim.x * NPB;
    const float2v z2 = splat2(0.f);

    for (; v < N; v += vstride) {
        const int e0 = row_start[v];
        const int e1 = row_start[v + 1];
        float2v acc = z2;

        int i = e0;
        if (i + 8 <= e1) {
            int2 c2 = csr[i + (lane >> 3)];  // 8 edges x {eid, src}
            while (true) {
                int eid[8], se[8];
#pragma unroll
                for (int j = 0; j < 8; ++j) {
                    eid[j] = __builtin_amdgcn_readlane(c2.x, j * 8);
                    se[j] = __builtin_amdgcn_readlane(c2.y, j * 8);
                }
                const int inext = i + 8;
                const bool more = (inext + 8 <= e1);
                int2 c2n;
                if (more) c2n = csr[inext + (lane >> 3)];  // prefetch next block
                ushort2 r[8];
#pragma unroll
                for (int j = 0; j < 8; ++j)  // 8 gathers in flight
                    r[j] = *(const ushort2*)&hb[(size_t)se[j] * D + ch0];
#pragma unroll
                for (int j = 0; j < 8; ++j) {
                    float2v hv;
                    hv[0] = bf2f(r[j].x);
                    hv[1] = bf2f(r[j].y);
                    acc += edge_term(ea, eid[j], w, bias, hv, z2);
                }
                i = inext;
                if (!more) break;
                c2 = c2n;
            }
        }
        if (i + 4 <= e1) {  // 4-edge tail chunk
            int2 c2 = csr[i + (lane >> 4)];
            int eid[4], se[4];
#pragma unroll
            for (int j = 0; j < 4; ++j) {
                eid[j] = __builtin_amdgcn_readlane(c2.x, j * 16);
                se[j] = __builtin_amdgcn_readlane(c2.y, j * 16);
            }
            ushort2 r[4];
#pragma unroll
            for (int j = 0; j < 4; ++j)
                r[j] = *(const ushort2*)&hb[(size_t)se[j] * D + ch0];
#pragma unroll
            for (int j = 0; j < 4; ++j) {
                float2v hv;
                hv[0] = bf2f(r[j].x);
                hv[1] = bf2f(r[j].y);
                acc += edge_term(ea, eid[j], w, bias, hv, z2);
            }
            i += 4;
        }
        for (; i < e1; ++i) {  // <=3 single edges
            int2 ce = csr[i];
            ushort2 r = *(const ushort2*)&hb[(size_t)ce.y * D + ch0];
            float2v hv;
            hv[0] = bf2f(r.x);
            hv[1] = bf2f(r.y);
            acc += edge_term(ea, ce.x, w, bias, hv, z2);
        }
        // epilogue: u = h_v + acc -> bf16 hi/lo
        float2v sv = *(const float2v*)&h[(size_t)v * D + ch0];
        float u0 = sv[0] + acc[0];
        float u1 = sv[1] + acc[1];
        ushort h0 = f2bf_rne(u0);
        ushort h1 = f2bf_rne(u1);
        ushort l0 = f2bf_rne(u0 - bf2f(h0));
        ushort l1 = f2bf_rne(u1 - bf2f(h1));
        *(ushort2*)&uhi[(size_t)v * D + ch0] = make_ushort2(h0, h1);
        *(ushort2*)&ulo[(size_t)v * D + ch0] = make_ushort2(l0, l1);
    }
}

// ---------------- Split-bf16 MFMA GEMM (+ optional fused BN stats) ---------
template <int WRITE_BF16, int STATS>
__global__ __launch_bounds__(256) void gemm_mfma(
    const ushort* __restrict__ Ah, const ushort* __restrict__ Al,
    const ushort* __restrict__ Bh, const ushort* __restrict__ Bl,
    const float* __restrict__ bias,
    float* __restrict__ Cf, ushort* __restrict__ Chi, ushort* __restrict__ Clo,
    float* __restrict__ stats, int Nreal,
    int N, int K, int relu) {
    __shared__ ushort sA[2][128][72];
    __shared__ ushort sB[2][64][72];
    const int tid = threadIdx.x;
    const int wave = tid >> 6, lane = tid & 63;
    const int lrow = lane & 15, lquad = lane >> 4;
    const int bm = blockIdx.y * 128;
    const int bn = blockIdx.x * 64;

    floatx4 acc[2][4];
#pragma unroll
    for (int i = 0; i < 2; ++i)
#pragma unroll
        for (int j = 0; j < 4; ++j) acc[i][j] = (floatx4)0.f;

    for (int k0 = 0; k0 < K; k0 += 64) {
        for (int s = tid; s < 1024; s += 256) {
            int row = s >> 3, c8 = (s & 7) * 8;
            size_t g = (size_t)(bm + row) * K + k0 + c8;
            *(int4*)&sA[0][row][c8] = *(const int4*)&Ah[g];
            *(int4*)&sA[1][row][c8] = *(const int4*)&Al[g];
        }
        for (int s = tid; s < 512; s += 256) {
            int row = s >> 3, c8 = (s & 7) * 8;
            size_t g = (size_t)(bn + row) * K + k0 + c8;
            *(int4*)&sB[0][row][c8] = *(const int4*)&Bh[g];
            *(int4*)&sB[1][row][c8] = *(const int4*)&Bl[g];
        }
        __syncthreads();
        const int rb = wave * 32;
#pragma unroll
        for (int kk = 0; kk < 2; ++kk) {
            int ko = kk * 32 + lquad * 8;
            short8 ah[2], al[2], bh[4], bl[4];
#pragma unroll
            for (int i = 0; i < 2; ++i) {
                ah[i] = *(const short8*)&sA[0][rb + i * 16 + lrow][ko];
                al[i] = *(const short8*)&sA[1][rb + i * 16 + lrow][ko];
            }
#pragma unroll
            for (int j = 0; j < 4; ++j) {
                bh[j] = *(const short8*)&sB[0][j * 16 + lrow][ko];
                bl[j] = *(const short8*)&sB[1][j * 16 + lrow][ko];
            }
#pragma unroll
            for (int i = 0; i < 2; ++i)
#pragma unroll
                for (int j = 0; j < 4; ++j) {
                    acc[i][j] = __builtin_amdgcn_mfma_f32_16x16x32_bf16(
                        ah[i], bh[j], acc[i][j], 0, 0, 0);
                    acc[i][j] = __builtin_amdgcn_mfma_f32_16x16x32_bf16(
                        ah[i], bl[j], acc[i][j], 0, 0, 0);
                    acc[i][j] = __builtin_amdgcn_mfma_f32_16x16x32_bf16(
                        al[i], bh[j], acc[i][j], 0, 0, 0);
                }
        }
        __syncthreads();
    }
    float sj[4] = {0.f, 0.f, 0.f, 0.f};
    float qj[4] = {0.f, 0.f, 0.f, 0.f};
#pragma unroll
    for (int i = 0; i < 2; ++i)
#pragma unroll
        for (int j = 0; j < 4; ++j) {
            int gc = bn + j * 16 + lrow;
            float bv = bias[gc];
#pragma unroll
            for (int r = 0; r < 4; ++r) {
                int gr = bm + wave * 32 + i * 16 + lquad * 4 + r;
                float v = acc[i][j][r] + bv;
                if (relu) v = fmaxf(v, 0.f);
                if (STATS && gr < Nreal) {
                    sj[j] += v;
                    qj[j] = fmaf(v, v, qj[j]);
                }
                if (WRITE_BF16) {
                    ushort hv = f2bf_rne(v);
                    ushort lv = f2bf_rne(v - bf2f(hv));
                    Chi[(size_t)gr * N + gc] = hv;
                    Clo[(size_t)gr * N + gc] = lv;
                } else {
                    Cf[(size_t)gr * N + gc] = v;
                }
            }
        }
    if (STATS) {
#pragma unroll
        for (int j = 0; j < 4; ++j) {
            float s = sj[j], q = qj[j];
            s += __shfl_xor(s, 16);
            s += __shfl_xor(s, 32);
            q += __shfl_xor(q, 16);
            q += __shfl_xor(q, 32);
            if (lquad == 0) {
                int gc = bn + j * 16 + lrow;
                atomicAdd(&stats[gc], s);
                atomicAdd(&stats[N + gc], q);
            }
        }
    }
}

// ---------------- BatchNorm apply (vectorized, + bf16 copy) ----------------
__global__ __launch_bounds__(256) void bn_apply_kernel(
    const float* __restrict__ r, float* __restrict__ h,
    ushort* __restrict__ hbout,
    const float* __restrict__ sums,
    const float* __restrict__ g, const float* __restrict__ bt,
    int N, int D, int Dm1) {
    int idx = blockIdx.x * blockDim.x + threadIdx.x;
    int total4 = N * D / 4;
    int stride = gridDim.x * blockDim.x;
    float invN = 1.0f / (float)N;
    for (; idx < total4; idx += stride) {
        int c = (idx * 4) & Dm1;
        float4 s4 = *(const float4*)&sums[c];
        float4 q4 = *(const float4*)&sums[D + c];
        float4 g4 = *(const float4*)&g[c];
        float4 b4 = *(const float4*)&bt[c];
        float4 r4 = ((const float4*)r)[idx];
        float4 o;
        {
            float mu = s4.x * invN;
            float var = fmaf(-mu, mu, q4.x * invN);
            o.x = (r4.x - mu) * (rsqrtf(var + 1e-5f) * g4.x) + b4.x;
            mu = s4.y * invN;
            var = fmaf(-mu, mu, q4.y * invN);
            o.y = (r4.y - mu) * (rsqrtf(var + 1e-5f) * g4.y) + b4.y;
            mu = s4.z * invN;
            var = fmaf(-mu, mu, q4.z * invN);
            o.z = (r4.z - mu) * (rsqrtf(var + 1e-5f) * g4.z) + b4.z;
            mu = s4.w * invN;
            var = fmaf(-mu, mu, q4.w * invN);
            o.w = (r4.w - mu) * (rsqrtf(var + 1e-5f) * g4.w) + b4.w;
        }
        ((float4*)h)[idx] = o;
        if (hbout) {
            ushort4 ob;
            ob.x = f2bf_rne(o.x);
            ob.y = f2bf_rne(o.y);
            ob.z = f2bf_rne(o.z);
            ob.w = f2bf_rne(o.w);
            ((ushort4*)hbout)[idx] = ob;
        }
    }
}

// ---------------- Head ----------------
__global__ void head_kernel(const float* __restrict__ h, const int* __restrict__ n_nodes,
                            const float* __restrict__ Wf1, const float* __restrict__ bf1,
                            const float* __restrict__ Wf2, const float* __restrict__ bf2,
                            float* __restrict__ out, int G) {
    int g = blockIdx.x * blockDim.x + threadIdx.x;
    if (g >= G) return;
    int s = 0;
    for (int i = 0; i <= g; ++i) s += n_nodes[i];
    const float* m = &h[(size_t)(s - 1) * 64];
    float o = bf2[0];
#pragma unroll 4
    for (int j = 0; j < 16; ++j) {
        float acc = bf1[j];
        for (int k = 0; k < 64; ++k) acc = fmaf(m[k], Wf1[k * 16 + j], acc);
        acc = fmaxf(acc, 0.f);
        o = fmaf(acc, Wf2[j], o);
    }
    out[g] = o;
}

extern "C" void kernel_launch(void* const* d_in, const int* in_sizes, int n_in,
                              void* d_out, int out_size, void* d_ws, size_t ws_size,
                              hipStream_t stream) {
    const float* x = (const float*)d_in[0];
    const float* ea = (const float*)d_in[1];
    const int* eidx = (const int*)d_in[2];
    const int* n_nodes = (const int*)d_in[3];
    const float* We1 = (const float*)d_in[4];
    const float* be1 = (const float*)d_in[5];
    const float* W11 = (const float*)d_in[6];
    const float* b11 = (const float*)d_in[7];
    const float* W12 = (const float*)d_in[8];
    const float* b12 = (const float*)d_in[9];
    const float* g1 = (const float*)d_in[10];
    const float* bt1 = (const float*)d_in[11];
    const float* We2 = (const float*)d_in[12];
    const float* be2 = (const float*)d_in[13];
    const float* W21 = (const float*)d_in[14];
    const float* b21 = (const float*)d_in[15];
    const float* W22 = (const float*)d_in[16];
    const float* b22 = (const float*)d_in[17];
    const float* g2 = (const float*)d_in[18];
    const float* bt2 = (const float*)d_in[19];
    const float* We3 = (const float*)d_in[20];
    const float* be3 = (const float*)d_in[21];
    const float* W31 = (const float*)d_in[22];
    const float* b31 = (const float*)d_in[23];
    const float* W32 = (const float*)d_in[24];
    const float* b32 = (const float*)d_in[25];
    const float* g3 = (const float*)d_in[26];
    const float* bt3 = (const float*)d_in[27];
    const float* Wf1 = (const float*)d_in[28];
    const float* bf1 = (const float*)d_in[29];
    const float* Wf2 = (const float*)d_in[30];
    const float* bf2 = (const float*)d_in[31];

    const int N = in_sizes[0] / 128;  // 50000
    const int E = in_sizes[2] / 2;    // 800000
    const int G = in_sizes[3];        // 500
    const int Mp = ((N + 127) / 128) * 128;  // 50048
    const int* srcp = eidx;
    const int* dstp = eidx + E;

    float* H = (float*)d_ws;            // Mp x 256 fp32
    float* UR = H + (size_t)Mp * 256;   // Mp x 256: u(hi/lo bf16) / r(fp32)
    float* TT = UR + (size_t)Mp * 256;  // Mp x 256: t(hi/lo bf16) / hb(bf16)
    float* stats1 = TT + (size_t)Mp * 256;  // 512
    float* stats2 = stats1 + 512;           // 256
    float* stats3 = stats2 + 256;           // 128
    int* deg = (int*)(stats3 + 128);        // N
    int* cursor = deg + N;                  // N
    int* row_start = cursor + N;            // N+1 (+1 pad for int2 align)
    int2* csr = (int2*)(row_start + N + 2); // E int2
    size_t woff = (size_t)((int*)(csr + E) - (int*)d_ws);
    woff = (woff + 3) & ~(size_t)3;
    ushort* wp = (ushort*)((int*)d_ws + woff);
    ushort* W11th = wp; wp += 128 * 256;
    ushort* W11tl = wp; wp += 128 * 256;
    ushort* W12th = wp; wp += 256 * 256;
    ushort* W12tl = wp; wp += 256 * 256;
    ushort* W21th = wp; wp += 256 * 128;
    ushort* W21tl = wp; wp += 256 * 128;
    ushort* W22th = wp; wp += 128 * 128;
    ushort* W22tl = wp; wp += 128 * 128;
    ushort* W31th = wp; wp += 128 * 64;
    ushort* W31tl = wp; wp += 128 * 64;
    ushort* W32th = wp; wp += 64 * 64;
    ushort* W32tl = wp; wp += 64 * 64;

    hipMemsetAsync(stats1, 0, 896 * sizeof(float) + (size_t)2 * N * sizeof(int), stream);

    const int prepTot = 128 * 256 + 256 * 256 + 256 * 128 + 128 * 128 + 128 * 64 + 64 * 64;
    prep_all<<<(prepTot + 255) / 256, 256, 0, stream>>>(
        W11, W11th, W11tl, W12, W12th, W12tl, W21, W21th, W21tl,
        W22, W22th, W22tl, W31, W31th, W31tl, W32, W32th, W32tl);

    hist_kernel<<<3125, 256, 0, stream>>>(dstp, deg, E);
    scan_kernel<<<1, 1024, 0, stream>>>(deg, row_start, N);
    scatter_kernel<<<3125, 256, 0, stream>>>(srcp, dstp, row_start, cursor, csr, E);

    const int gy = Mp / 128;
    float* R = UR;
    ushort* HB = (ushort*)TT;  // bf16 gather copy lives in the (dead) TT region

    // ---------------- Layer 1: 128 -> 256 -> 256 ----------------
    {
        ushort* Uhi = (ushort*)UR; ushort* Ulo = Uhi + (size_t)Mp * 128;
        ushort* Thi = (ushort*)TT; ushort* Tlo = Thi + (size_t)Mp * 256;
        f32_to_bf16<<<2048, 256, 0, stream>>>(x, HB, (long)N * 128 / 4);
        gine_agg_kernel<128, 1><<<(N + 3) / 4, 256, 0, stream>>>(
            x, HB, ea, row_start, csr, We1, be1, Uhi, Ulo, N);
        gemm_mfma<1, 0><<<dim3(4, gy), 256, 0, stream>>>(
            Uhi, Ulo, W11th, W11tl, b11, nullptr, Thi, Tlo, nullptr, 0, 256, 128, 1);
        gemm_mfma<0, 1><<<dim3(4, gy), 256, 0, stream>>>(
            Thi, Tlo, W12th, W12tl, b12, R, nullptr, nullptr, stats1, N, 256, 256, 1);
        bn_apply_kernel<<<2048, 256, 0, stream>>>(R, H, HB, stats1, g1, bt1, N, 256, 255);
    }

    // ---------------- Layer 2: 256 -> 128 -> 128 ----------------
    {
        ushort* Uhi = (ushort*)UR; ushort* Ulo = Uhi + (size_t)Mp * 256;
        ushort* Thi = (ushort*)TT; ushort* Tlo = Thi + (size_t)Mp * 128;
        gine_agg_kernel<256, 2><<<(N + 1) / 2, 256, 0, stream>>>(
            H, HB, ea, row_start, csr, We2, be2, Uhi, Ulo, N);
        gemm_mfma<1, 0><<<dim3(2, gy), 256, 0, stream>>>(
            Uhi, Ulo, W21th, W21tl, b21, nullptr, Thi, Tlo, nullptr, 0, 128, 256, 1);
        gemm_mfma<0, 1><<<dim3(2, gy), 256, 0, stream>>>(
            Thi, Tlo, W22th, W22tl, b22, R, nullptr, nullptr, stats2, N, 128, 128, 1);
        bn_apply_kernel<<<2048, 256, 0, stream>>>(R, H, HB, stats2, g2, bt2, N, 128, 127);
    }

    // ---------------- Layer 3: 128 -> 64 -> 64 ----------------
    {
        ushort* Uhi = (ushort*)UR; ushort* Ulo = Uhi + (size_t)Mp * 128;
        ushort* Thi = (ushort*)TT; ushort* Tlo = Thi + (size_t)Mp * 64;
        gine_agg_kernel<128, 1><<<(N + 3) / 4, 256, 0, stream>>>(
            H, HB, ea, row_start, csr, We3, be3, Uhi, Ulo, N);
        gemm_mfma<1, 0><<<dim3(1, gy), 256, 0, stream>>>(
            Uhi, Ulo, W31th, W31tl, b31, nullptr, Thi, Tlo, nullptr, 0, 64, 128, 1);
        gemm_mfma<0, 1><<<dim3(1, gy), 256, 0, stream>>>(
            Thi, Tlo, W32th, W32tl, b32, R, nullptr, nullptr, stats3, N, 64, 64, 1);
        bn_apply_kernel<<<2048, 256, 0, stream>>>(R, H, nullptr, stats3, g3, bt3, N, 64, 63);
    }

    // ---------------- Head ----------------
    head_kernel<<<(G + 255) / 256, 256, 0, stream>>>(H, n_nodes, Wf1, bf1, Wf2, bf2,
                                                     (float*)d_out, G);
}